// Round 14
// baseline (397.333 us; speedup 1.0000x reference)
//
#include <hip/hip_runtime.h>

// DigitCapsules dynamic routing. Round-14: MULTI-KERNEL PHASE SPLIT.
//  - 13 rounds of single-kernel tuning all orbit ~220-250 us because the
//    fused design pins the machine at 1 block/CU, 1 wave/SIMD, ~90% stall.
//    Kernel launches are cheap grid-wide syncs under graph replay -> split
//    phases into kernels with REAL occupancy (9 blocks/CU, 18 waves/CU):
//      k_uhat_s0 : thread=capsule. u_hat from Wt (16-row batch), store ut,
//                  wave-reduce + atomicAdd s0. No barriers.
//      k_squash  : one wave per (b,c): squash s -> v (packed f16) or out.
//      k_route   : thread=capsule. Load u for ALL 10 classes once (80 regs),
//                  fused agreement + blog + softmax + weighted-sum atomicAdd
//                  into s_next. One barrier (v broadcast). Kills R13's
//                  double ut re-read.
//  - s buffers zeroed via hipMemsetAsync (graph-capture-safe, done per call).
//  - Cross-kernel visibility: same-stream kernel boundaries flush/acquire L2.
//  - Atomic contention: 18 adders per s address. f32 atomicAdd device-scope.
//  - Kept proven pieces: f16 Wt[c][d][i] + v_dot2_f32_f16 (absmax 0.0039),
//    ut[b][c][h][i] u4 layout (16 B lane stride), it0 softmax(0)=0.1.

#define NCLS   10
#define NCAPS  1152
#define KDO    16
#define CHUNK  128
#define NCH    9           // 1152 / 128
#define NB     256

typedef _Float16 h2_t __attribute__((ext_vector_type(2)));
typedef unsigned u4 __attribute__((ext_vector_type(4)));

static __device__ __forceinline__ unsigned pack2h(float a, float b) {
    union { _Float16 h[2]; unsigned u; } p;
    p.h[0] = (_Float16)a;
    p.h[1] = (_Float16)b;
    return p.u;
}

static __device__ __forceinline__ float dot8h(u4 r, const unsigned* xh) {
    union { unsigned u; h2_t h; } w0, w1, w2, w3, a0, a1, a2, a3;
    w0.u = r.x; w1.u = r.y; w2.u = r.z; w3.u = r.w;
    a0.u = xh[0]; a1.u = xh[1]; a2.u = xh[2]; a3.u = xh[3];
#if __has_builtin(__builtin_amdgcn_fdot2)
    float acc = __builtin_amdgcn_fdot2(w0.h, a0.h, 0.f, false);
    acc = __builtin_amdgcn_fdot2(w1.h, a1.h, acc, false);
    acc = __builtin_amdgcn_fdot2(w2.h, a2.h, acc, false);
    acc = __builtin_amdgcn_fdot2(w3.h, a3.h, acc, false);
    return acc;
#else
    return (float)w0.h.x * (float)a0.h.x + (float)w0.h.y * (float)a0.h.y
         + (float)w1.h.x * (float)a1.h.x + (float)w1.h.y * (float)a1.h.y
         + (float)w2.h.x * (float)a2.h.x + (float)w2.h.y * (float)a2.h.y
         + (float)w3.h.x * (float)a3.h.x + (float)w3.h.y * (float)a3.h.y;
#endif
}

static __device__ __forceinline__ float dot2h(unsigned a, unsigned b, float acc) {
    union { unsigned u; h2_t h; } pa, pb;
    pa.u = a; pb.u = b;
#if __has_builtin(__builtin_amdgcn_fdot2)
    return __builtin_amdgcn_fdot2(pa.h, pb.h, acc, false);
#else
    return acc + (float)pa.h.x * (float)pb.h.x + (float)pa.h.y * (float)pb.h.y;
#endif
}

// Wt[c][d][i] : u4 holding f16 W[c,i,0,d,k] for k=0..7
__global__ __launch_bounds__(256)
void pack_W_f16(const float4* __restrict__ W4, u4* __restrict__ Wt) {
    int tid = blockIdx.x * blockDim.x + threadIdx.x;   // (c*NCAPS+i)*KDO + d
    if (tid >= NCLS * NCAPS * KDO) return;
    int d = tid & 15;
    int rest = tid >> 4;
    int i = rest % NCAPS;
    int c = rest / NCAPS;
    float4 a = W4[2 * tid];
    float4 b = W4[2 * tid + 1];
    u4 o;
    o.x = pack2h(a.x, a.y);
    o.y = pack2h(a.z, a.w);
    o.z = pack2h(b.x, b.y);
    o.w = pack2h(b.z, b.w);
    Wt[(size_t)(c * KDO + d) * NCAPS + i] = o;
}

// ---- phase 1: u_hat + unweighted s0 (scaled 0.1 in squash). No barriers. ----
__global__ __launch_bounds__(CHUNK, 1)
void k_uhat_s0(const u4* __restrict__ Wt, const float* __restrict__ x,
               u4* __restrict__ ut, float* __restrict__ s0)
{
    const int t    = threadIdx.x;
    const int lane = t & 63;
    const int ii   = blockIdx.x * CHUNK + t;
    const int b    = blockIdx.y;

    const float4* x4 = reinterpret_cast<const float4*>(x) + (size_t)b * NCAPS * 2;
    float4 x0 = x4[2 * ii];
    float4 x1 = x4[2 * ii + 1];
    unsigned xh[4] = { pack2h(x0.x, x0.y), pack2h(x0.z, x0.w),
                       pack2h(x1.x, x1.y), pack2h(x1.z, x1.w) };
    u4* utb = ut + (size_t)b * NCLS * 2 * NCAPS;
    float* s0b = s0 + (size_t)b * NCLS * KDO;

    #pragma unroll 1
    for (int c = 0; c < NCLS; ++c) {
        const u4* base = Wt + (size_t)c * KDO * NCAPS + ii;
        u4 r[KDO];                                // all 16 loads in flight
        #pragma unroll
        for (int d = 0; d < KDO; ++d)
            r[d] = __builtin_nontemporal_load(base + (size_t)d * NCAPS);
        float u[KDO];
        u4 h0, h1;
        #pragma unroll
        for (int dp = 0; dp < 8; ++dp) {
            float u0 = dot8h(r[2 * dp],     xh);
            float u1 = dot8h(r[2 * dp + 1], xh);
            u[2 * dp] = u0; u[2 * dp + 1] = u1;
            unsigned pk = pack2h(u0, u1);
            if (dp < 4) ((unsigned*)&h0)[dp] = pk;
            else        ((unsigned*)&h1)[dp - 4] = pk;
        }
        utb[((size_t)c * 2 + 0) * NCAPS + ii] = h0;
        utb[((size_t)c * 2 + 1) * NCAPS + ii] = h1;

        #pragma unroll
        for (int d = 0; d < KDO; ++d) {           // wave reduce, lane0 atomics
            float v = u[d];
            v += __shfl_xor(v, 32, 64);
            v += __shfl_xor(v, 16, 64);
            v += __shfl_xor(v,  8, 64);
            v += __shfl_xor(v,  4, 64);
            v += __shfl_xor(v,  2, 64);
            v += __shfl_xor(v,  1, 64);
            if (lane == 0) atomicAdd(&s0b[c * KDO + d], v);
        }
    }
}

// ---- phase 2: squash. One wave per (b,c). ----
__global__ __launch_bounds__(256, 1)
void k_squash(const float* __restrict__ s, float scale,
              unsigned* __restrict__ vph, float* __restrict__ out, int last)
{
    int gw   = blockIdx.x * 4 + (threadIdx.x >> 6);   // b*NCLS + c
    int lane = threadIdx.x & 63;
    if (gw >= NB * NCLS) return;
    float v = 0.f;
    if (lane < KDO) v = s[(size_t)gw * KDO + lane] * scale;
    float nsq = v * v;
    nsq += __shfl_xor(nsq, 8, 16);
    nsq += __shfl_xor(nsq, 4, 16);
    nsq += __shfl_xor(nsq, 2, 16);
    nsq += __shfl_xor(nsq, 1, 16);
    float sc = sqrtf(nsq) / (1.f + nsq);              // (nsq/(1+nsq))/sqrt(nsq)
    float vv = v * sc;
    if (last) {
        if (lane < KDO) out[(size_t)gw * KDO + lane] = vv;
    } else {
        float a = __shfl(vv, 2 * (lane & 7), 64);
        float b = __shfl(vv, 2 * (lane & 7) + 1, 64);
        if (lane < 8) vph[(size_t)gw * 8 + lane] = pack2h(a, b);
    }
}

// ---- phase 3: fused agreement + blog + softmax + weighted s_next. ----
__global__ __launch_bounds__(CHUNK, 1)
void k_route(const u4* __restrict__ ut, const unsigned* __restrict__ vph,
             float* __restrict__ blog, float* __restrict__ s_next,
             int first, int store_blog)
{
    __shared__ unsigned vsh[NCLS * 8];                // v packed f16, 320 B
    const int t    = threadIdx.x;
    const int lane = t & 63;
    const int ii   = blockIdx.x * CHUNK + t;
    const int b    = blockIdx.y;

    if (t < NCLS * 8) vsh[t] = vph[(size_t)b * NCLS * 8 + t];
    __syncthreads();

    const u4* utb = ut + (size_t)b * NCLS * 2 * NCAPS;
    float* blogb = blog + (size_t)b * NCLS * NCAPS;
    float* snb = s_next + (size_t)b * NCLS * KDO;

    u4 up0[NCLS], up1[NCLS];                          // 80 VGPRs: u for all classes
    #pragma unroll
    for (int c = 0; c < NCLS; ++c) {
        up0[c] = utb[((size_t)c * 2 + 0) * NCAPS + ii];
        up1[c] = utb[((size_t)c * 2 + 1) * NCAPS + ii];
    }

    float bl[NCLS];
    #pragma unroll
    for (int c = 0; c < NCLS; ++c) {
        float a = first ? 0.f : blogb[(size_t)c * NCAPS + ii];
        #pragma unroll
        for (int dp = 0; dp < 4; ++dp)
            a = dot2h(((const unsigned*)&up0[c])[dp], vsh[c * 8 + dp], a);
        #pragma unroll
        for (int dp = 0; dp < 4; ++dp)
            a = dot2h(((const unsigned*)&up1[c])[dp], vsh[c * 8 + 4 + dp], a);
        bl[c] = a;
        if (store_blog) blogb[(size_t)c * NCAPS + ii] = a;
    }

    float m = bl[0];
    #pragma unroll
    for (int c = 1; c < NCLS; ++c) m = fmaxf(m, bl[c]);
    float den = 0.f;
    #pragma unroll
    for (int c = 0; c < NCLS; ++c) den += __expf(bl[c] - m);
    float sid = 1.f / den;

    #pragma unroll 1
    for (int c = 0; c < NCLS; ++c) {
        float w = __expf(bl[c] - m) * sid;
        #pragma unroll
        for (int d = 0; d < KDO; ++d) {
            union { unsigned u; h2_t h; } p;
            p.u = (d < 8) ? ((const unsigned*)&up0[c])[d >> 1]
                          : ((const unsigned*)&up1[c])[(d - 8) >> 1];
            float uv = (d & 1) ? (float)p.h.y : (float)p.h.x;
            float v = w * uv;
            v += __shfl_xor(v, 32, 64);
            v += __shfl_xor(v, 16, 64);
            v += __shfl_xor(v,  8, 64);
            v += __shfl_xor(v,  4, 64);
            v += __shfl_xor(v,  2, 64);
            v += __shfl_xor(v,  1, 64);
            if (lane == 0) atomicAdd(&snb[c * KDO + d], v);
        }
    }
}

// ---- fallback (small ws): round-1 fp32 fused kernel, proven correct ----
__global__ __launch_bounds__(256, 2)
void caps_routing_fb(const float* __restrict__ x, const float* __restrict__ W,
                     float* __restrict__ out)
{
    const int b    = blockIdx.x;
    const int t    = threadIdx.x;
    const int lane = t & 63;
    const int wave = t >> 6;
    __shared__ float v_prev[NCLS * KDO];
    __shared__ float redf[NCLS * 4 * KDO];
    float4 xr[5][2];
    const float4* x4 = reinterpret_cast<const float4*>(x + (size_t)b * NCAPS * 8);
    #pragma unroll
    for (int j = 0; j < 5; ++j) {
        int i = t + 256 * j;
        if (i < NCAPS) { xr[j][0] = x4[2 * i]; xr[j][1] = x4[2 * i + 1]; }
    }
    float blog[5][NCLS];
    #pragma unroll
    for (int j = 0; j < 5; ++j)
        #pragma unroll
        for (int c = 0; c < NCLS; ++c) blog[j][c] = 0.f;
    const float4* W4 = reinterpret_cast<const float4*>(W);
    for (int it = 0; it < 3; ++it) {
        if (it > 0) {
            for (int c = 0; c < NCLS; ++c) {
                float vp[KDO];
                #pragma unroll
                for (int d = 0; d < KDO; ++d) vp[d] = v_prev[c * KDO + d];
                #pragma unroll
                for (int j = 0; j < 5; ++j) {
                    int i = t + 256 * j;
                    if (i < NCAPS) {
                        size_t wb = (size_t)(c * NCAPS + i) * 32;
                        float a = 0.f;
                        #pragma unroll
                        for (int d = 0; d < KDO; ++d) {
                            float4 w0 = W4[wb + 2 * d]; float4 w1 = W4[wb + 2 * d + 1];
                            float u = w0.x*xr[j][0].x + w0.y*xr[j][0].y + w0.z*xr[j][0].z
                                    + w0.w*xr[j][0].w + w1.x*xr[j][1].x + w1.y*xr[j][1].y
                                    + w1.z*xr[j][1].z + w1.w*xr[j][1].w;
                            a += u * vp[d];
                        }
                        blog[j][c] += a;
                    }
                }
            }
        }
        float sm2[5], sid2[5];
        #pragma unroll
        for (int j = 0; j < 5; ++j) {
            int i = t + 256 * j;
            if (i < NCAPS) {
                float m = blog[j][0];
                #pragma unroll
                for (int c = 1; c < NCLS; ++c) m = fmaxf(m, blog[j][c]);
                float den = 0.f;
                #pragma unroll
                for (int c = 0; c < NCLS; ++c) den += __expf(blog[j][c] - m);
                sm2[j] = m; sid2[j] = 1.f / den;
            }
        }
        for (int c = 0; c < NCLS; ++c) {
            float acc[KDO];
            #pragma unroll
            for (int d = 0; d < KDO; ++d) acc[d] = 0.f;
            #pragma unroll
            for (int j = 0; j < 5; ++j) {
                int i = t + 256 * j;
                if (i < NCAPS) {
                    float w = __expf(blog[j][c] - sm2[j]) * sid2[j];
                    size_t wb = (size_t)(c * NCAPS + i) * 32;
                    #pragma unroll
                    for (int d = 0; d < KDO; ++d) {
                        float4 w0 = W4[wb + 2 * d]; float4 w1 = W4[wb + 2 * d + 1];
                        float u = w0.x*xr[j][0].x + w0.y*xr[j][0].y + w0.z*xr[j][0].z
                                + w0.w*xr[j][0].w + w1.x*xr[j][1].x + w1.y*xr[j][1].y
                                + w1.z*xr[j][1].z + w1.w*xr[j][1].w;
                        acc[d] += w * u;
                    }
                }
            }
            #pragma unroll
            for (int d = 0; d < KDO; ++d) {
                float v = acc[d];
                v += __shfl_xor(v, 32, 64); v += __shfl_xor(v, 16, 64);
                v += __shfl_xor(v,  8, 64); v += __shfl_xor(v,  4, 64);
                v += __shfl_xor(v,  2, 64); v += __shfl_xor(v,  1, 64);
                if (lane == 0) redf[(c * 4 + wave) * KDO + d] = v;
            }
        }
        __syncthreads();
        if (t < NCLS * KDO) {
            int c = t >> 4, d = t & 15;
            float s = redf[(c*4+0)*KDO+d] + redf[(c*4+1)*KDO+d]
                    + redf[(c*4+2)*KDO+d] + redf[(c*4+3)*KDO+d];
            float nsq = s * s;
            nsq += __shfl_xor(nsq, 8, 16); nsq += __shfl_xor(nsq, 4, 16);
            nsq += __shfl_xor(nsq, 2, 16); nsq += __shfl_xor(nsq, 1, 16);
            float scale = sqrtf(nsq) / (1.f + nsq);
            float vv = s * scale;
            v_prev[t] = vv;
            if (it == 2) out[(size_t)b * NCLS * KDO + t] = vv;
        }
        __syncthreads();
    }
}

extern "C" void kernel_launch(void* const* d_in, const int* in_sizes, int n_in,
                              void* d_out, int out_size, void* d_ws, size_t ws_size,
                              hipStream_t stream) {
    const float* x = (const float*)d_in[0];              // [256, 1152, 8] fp32
    const float4* W4 = (const float4*)d_in[1];           // [10, 1152, 1, 16, 8] fp32
    float* out = (float*)d_out;                          // [256, 10, 1, 16] fp32
    (void)in_sizes; (void)n_in; (void)out_size;

    const size_t WT = (size_t)NCLS * KDO * NCAPS * sizeof(u4);       //  2.95 MB
    const size_t UT = (size_t)NB * NCLS * 2 * NCAPS * sizeof(u4);    // 94.37 MB
    const size_t BL = (size_t)NB * NCLS * NCAPS * sizeof(float);     // 11.80 MB
    const size_t SB = (size_t)NB * NCLS * KDO * sizeof(float);       //  160 KB
    const size_t VP = (size_t)NB * NCLS * 8 * sizeof(unsigned);      //   80 KB
    const size_t need = WT + UT + BL + 3 * SB + 2 * VP;              // ~109.9 MB

    if (ws_size >= need) {
        char* p = (char*)d_ws;
        u4* Wt       = (u4*)p;        p += WT;
        u4* ut       = (u4*)p;        p += UT;
        float* blog  = (float*)p;     p += BL;
        float* s0    = (float*)p;     p += SB;
        float* s1    = (float*)p;     p += SB;
        float* s2    = (float*)p;     p += SB;
        unsigned* v0 = (unsigned*)p;  p += VP;
        unsigned* v1 = (unsigned*)p;

        hipMemsetAsync(s0, 0, 3 * SB, stream);           // zero s0,s1,s2 (contiguous)

        int total = NCLS * NCAPS * KDO;
        pack_W_f16<<<dim3((total + 255) / 256), dim3(256), 0, stream>>>(W4, Wt);
        k_uhat_s0<<<dim3(NCH, NB), dim3(CHUNK), 0, stream>>>(Wt, x, ut, s0);
        k_squash<<<dim3(NB * NCLS / 4), dim3(256), 0, stream>>>(s0, 0.1f, v0, out, 0);
        k_route<<<dim3(NCH, NB), dim3(CHUNK), 0, stream>>>(ut, v0, blog, s1, 1, 1);
        k_squash<<<dim3(NB * NCLS / 4), dim3(256), 0, stream>>>(s1, 1.f, v1, out, 0);
        k_route<<<dim3(NCH, NB), dim3(CHUNK), 0, stream>>>(ut, v1, blog, s2, 0, 0);
        k_squash<<<dim3(NB * NCLS / 4), dim3(256), 0, stream>>>(s2, 1.f, v0, out, 1);
    } else {
        caps_routing_fb<<<dim3(NB), dim3(256), 0, stream>>>(x, (const float*)d_in[1], out);
    }
}

// Round 15
// 375.629 us; speedup vs baseline: 1.0578x; 1.0578x over previous
//
#include <hip/hip_runtime.h>

// DigitCapsules dynamic routing. Round-15 = Round-14 multi-kernel split with
// the two measured defects fixed:
//  1. k_route R14 spilled (VGPR 44 + 126 MB scratch WRITE): the weighted-sum
//     loop had runtime c indexing up0[c]/up1[c] -> arrays demoted to scratch
//     (the R3 disease). Now EVERY class loop in k_route is fully unrolled;
//     up/bl statically indexed -> register-resident (~140 VGPR, fine at
//     128-thread blocks).
//  2. k_uhat_s0 was dep-chain-limited (10 sequential class iters, 16 loads
//     in flight, 117 us @ 41% occ). Classes now split across gridDim.z
//     (5 z-slices x 2 classes, statically unrolled): 11520 blocks (5x the
//     parallelism), 32 loads in flight, per-thread chain cut 5x.
//  - Phase plan unchanged: pack_W -> k_uhat_s0 (u_hat + s0 atomics) ->
//    k_squash -> k_route(it0->1) -> k_squash -> k_route(it1->2) -> k_squash.
//    Kernel boundaries are the grid syncs; s buffers zeroed by memsetAsync.
//  - Proven pieces: f16 Wt[c][d][i] + v_dot2_f32_f16 (absmax 0.0039),
//    ut[b][c][h][i] u4 (16 B lane stride), it0 softmax(0)=0.1 shortcut.

#define NCLS   10
#define NCAPS  1152
#define KDO    16
#define CHUNK  128
#define NCH    9           // 1152 / 128
#define NB     256

typedef _Float16 h2_t __attribute__((ext_vector_type(2)));
typedef unsigned u4 __attribute__((ext_vector_type(4)));

static __device__ __forceinline__ unsigned pack2h(float a, float b) {
    union { _Float16 h[2]; unsigned u; } p;
    p.h[0] = (_Float16)a;
    p.h[1] = (_Float16)b;
    return p.u;
}

static __device__ __forceinline__ float dot8h(u4 r, const unsigned* xh) {
    union { unsigned u; h2_t h; } w0, w1, w2, w3, a0, a1, a2, a3;
    w0.u = r.x; w1.u = r.y; w2.u = r.z; w3.u = r.w;
    a0.u = xh[0]; a1.u = xh[1]; a2.u = xh[2]; a3.u = xh[3];
#if __has_builtin(__builtin_amdgcn_fdot2)
    float acc = __builtin_amdgcn_fdot2(w0.h, a0.h, 0.f, false);
    acc = __builtin_amdgcn_fdot2(w1.h, a1.h, acc, false);
    acc = __builtin_amdgcn_fdot2(w2.h, a2.h, acc, false);
    acc = __builtin_amdgcn_fdot2(w3.h, a3.h, acc, false);
    return acc;
#else
    return (float)w0.h.x * (float)a0.h.x + (float)w0.h.y * (float)a0.h.y
         + (float)w1.h.x * (float)a1.h.x + (float)w1.h.y * (float)a1.h.y
         + (float)w2.h.x * (float)a2.h.x + (float)w2.h.y * (float)a2.h.y
         + (float)w3.h.x * (float)a3.h.x + (float)w3.h.y * (float)a3.h.y;
#endif
}

static __device__ __forceinline__ float dot2h(unsigned a, unsigned b, float acc) {
    union { unsigned u; h2_t h; } pa, pb;
    pa.u = a; pb.u = b;
#if __has_builtin(__builtin_amdgcn_fdot2)
    return __builtin_amdgcn_fdot2(pa.h, pb.h, acc, false);
#else
    return acc + (float)pa.h.x * (float)pb.h.x + (float)pa.h.y * (float)pb.h.y;
#endif
}

static __device__ __forceinline__ float wave_sum(float v) {
    v += __shfl_xor(v, 32, 64);
    v += __shfl_xor(v, 16, 64);
    v += __shfl_xor(v,  8, 64);
    v += __shfl_xor(v,  4, 64);
    v += __shfl_xor(v,  2, 64);
    v += __shfl_xor(v,  1, 64);
    return v;
}

// Wt[c][d][i] : u4 holding f16 W[c,i,0,d,k] for k=0..7
__global__ __launch_bounds__(256)
void pack_W_f16(const float4* __restrict__ W4, u4* __restrict__ Wt) {
    int tid = blockIdx.x * blockDim.x + threadIdx.x;   // (c*NCAPS+i)*KDO + d
    if (tid >= NCLS * NCAPS * KDO) return;
    int d = tid & 15;
    int rest = tid >> 4;
    int i = rest % NCAPS;
    int c = rest / NCAPS;
    float4 a = W4[2 * tid];
    float4 b = W4[2 * tid + 1];
    u4 o;
    o.x = pack2h(a.x, a.y);
    o.y = pack2h(a.z, a.w);
    o.z = pack2h(b.x, b.y);
    o.w = pack2h(b.z, b.w);
    Wt[(size_t)(c * KDO + d) * NCAPS + i] = o;
}

// ---- phase 1: u_hat + unweighted s0. grid (NCH, NB, 5): 2 classes/block. ----
__global__ __launch_bounds__(CHUNK, 1)
void k_uhat_s0(const u4* __restrict__ Wt, const float* __restrict__ x,
               u4* __restrict__ ut, float* __restrict__ s0)
{
    const int t    = threadIdx.x;
    const int lane = t & 63;
    const int ii   = blockIdx.x * CHUNK + t;
    const int b    = blockIdx.y;
    const int c0   = blockIdx.z * 2;

    const float4* x4 = reinterpret_cast<const float4*>(x) + (size_t)b * NCAPS * 2;
    float4 x0 = x4[2 * ii];
    float4 x1 = x4[2 * ii + 1];
    unsigned xh[4] = { pack2h(x0.x, x0.y), pack2h(x0.z, x0.w),
                       pack2h(x1.x, x1.y), pack2h(x1.z, x1.w) };
    u4* utb = ut + (size_t)b * NCLS * 2 * NCAPS;
    float* s0b = s0 + (size_t)b * NCLS * KDO;

    // issue all 32 loads (2 classes x 16 rows) before any consumption
    u4 r[2][KDO];
    #pragma unroll
    for (int cc = 0; cc < 2; ++cc) {
        const u4* base = Wt + (size_t)(c0 + cc) * KDO * NCAPS + ii;
        #pragma unroll
        for (int d = 0; d < KDO; ++d)
            r[cc][d] = __builtin_nontemporal_load(base + (size_t)d * NCAPS);
    }

    #pragma unroll
    for (int cc = 0; cc < 2; ++cc) {
        const int c = c0 + cc;
        float u[KDO];
        u4 h0, h1;
        #pragma unroll
        for (int dp = 0; dp < 8; ++dp) {
            float u0 = dot8h(r[cc][2 * dp],     xh);
            float u1 = dot8h(r[cc][2 * dp + 1], xh);
            u[2 * dp] = u0; u[2 * dp + 1] = u1;
            unsigned pk = pack2h(u0, u1);
            if (dp < 4) ((unsigned*)&h0)[dp] = pk;
            else        ((unsigned*)&h1)[dp - 4] = pk;
        }
        utb[((size_t)c * 2 + 0) * NCAPS + ii] = h0;
        utb[((size_t)c * 2 + 1) * NCAPS + ii] = h1;

        #pragma unroll
        for (int d = 0; d < KDO; ++d) {
            float v = wave_sum(u[d]);
            if (lane == 0) atomicAdd(&s0b[c * KDO + d], v);
        }
    }
}

// ---- phase 2: squash. One wave per (b,c). ----
__global__ __launch_bounds__(256, 1)
void k_squash(const float* __restrict__ s, float scale,
              unsigned* __restrict__ vph, float* __restrict__ out, int last)
{
    int gw   = blockIdx.x * 4 + (threadIdx.x >> 6);   // b*NCLS + c
    int lane = threadIdx.x & 63;
    if (gw >= NB * NCLS) return;
    float v = 0.f;
    if (lane < KDO) v = s[(size_t)gw * KDO + lane] * scale;
    float nsq = v * v;
    nsq += __shfl_xor(nsq, 8, 16);
    nsq += __shfl_xor(nsq, 4, 16);
    nsq += __shfl_xor(nsq, 2, 16);
    nsq += __shfl_xor(nsq, 1, 16);
    float sc = sqrtf(nsq) / (1.f + nsq);              // (nsq/(1+nsq))/sqrt(nsq)
    float vv = v * sc;
    if (last) {
        if (lane < KDO) out[(size_t)gw * KDO + lane] = vv;
    } else {
        float a = __shfl(vv, 2 * (lane & 7), 64);
        float b = __shfl(vv, 2 * (lane & 7) + 1, 64);
        if (lane < 8) vph[(size_t)gw * 8 + lane] = pack2h(a, b);
    }
}

// ---- phase 3: agreement + blog + softmax + weighted s_next. ALL class loops
//      STATICALLY UNROLLED (R14's runtime-c indexing spilled up[] to scratch).
__global__ __launch_bounds__(CHUNK, 1)
void k_route(const u4* __restrict__ ut, const unsigned* __restrict__ vph,
             float* __restrict__ blog, float* __restrict__ s_next,
             int first, int store_blog)
{
    __shared__ unsigned vsh[NCLS * 8];                // v packed f16, 320 B
    const int t    = threadIdx.x;
    const int lane = t & 63;
    const int ii   = blockIdx.x * CHUNK + t;
    const int b    = blockIdx.y;

    if (t < NCLS * 8) vsh[t] = vph[(size_t)b * NCLS * 8 + t];
    __syncthreads();

    const u4* utb = ut + (size_t)b * NCLS * 2 * NCAPS;
    float* blogb = blog + (size_t)b * NCLS * NCAPS;
    float* snb = s_next + (size_t)b * NCLS * KDO;

    u4 up0[NCLS], up1[NCLS];                          // 80 VGPRs, static idx only
    #pragma unroll
    for (int c = 0; c < NCLS; ++c) {
        up0[c] = utb[((size_t)c * 2 + 0) * NCAPS + ii];
        up1[c] = utb[((size_t)c * 2 + 1) * NCAPS + ii];
    }

    float bl[NCLS];
    #pragma unroll
    for (int c = 0; c < NCLS; ++c) {
        float a = first ? 0.f : blogb[(size_t)c * NCAPS + ii];
        #pragma unroll
        for (int dp = 0; dp < 4; ++dp)
            a = dot2h(((const unsigned*)&up0[c])[dp], vsh[c * 8 + dp], a);
        #pragma unroll
        for (int dp = 0; dp < 4; ++dp)
            a = dot2h(((const unsigned*)&up1[c])[dp], vsh[c * 8 + 4 + dp], a);
        bl[c] = a;
        if (store_blog) blogb[(size_t)c * NCAPS + ii] = a;
    }

    float m = bl[0];
    #pragma unroll
    for (int c = 1; c < NCLS; ++c) m = fmaxf(m, bl[c]);
    float den = 0.f;
    #pragma unroll
    for (int c = 0; c < NCLS; ++c) den += __expf(bl[c] - m);
    float sid = 1.f / den;

    #pragma unroll
    for (int c = 0; c < NCLS; ++c) {                  // STATIC c throughout
        float w = __expf(bl[c] - m) * sid;
        #pragma unroll
        for (int dp = 0; dp < 8; ++dp) {
            union { unsigned u; h2_t h; } p;
            p.u = (dp < 4) ? ((const unsigned*)&up0[c])[dp]
                           : ((const unsigned*)&up1[c])[dp - 4];
            float v0 = wave_sum(w * (float)p.h.x);
            float v1 = wave_sum(w * (float)p.h.y);
            if (lane == 0) {
                atomicAdd(&snb[c * KDO + 2 * dp],     v0);
                atomicAdd(&snb[c * KDO + 2 * dp + 1], v1);
            }
        }
    }
}

// ---- fallback (small ws): round-1 fp32 fused kernel, proven correct ----
__global__ __launch_bounds__(256, 2)
void caps_routing_fb(const float* __restrict__ x, const float* __restrict__ W,
                     float* __restrict__ out)
{
    const int b    = blockIdx.x;
    const int t    = threadIdx.x;
    const int lane = t & 63;
    const int wave = t >> 6;
    __shared__ float v_prev[NCLS * KDO];
    __shared__ float redf[NCLS * 4 * KDO];
    float4 xr[5][2];
    const float4* x4 = reinterpret_cast<const float4*>(x + (size_t)b * NCAPS * 8);
    #pragma unroll
    for (int j = 0; j < 5; ++j) {
        int i = t + 256 * j;
        if (i < NCAPS) { xr[j][0] = x4[2 * i]; xr[j][1] = x4[2 * i + 1]; }
    }
    float blog[5][NCLS];
    #pragma unroll
    for (int j = 0; j < 5; ++j)
        #pragma unroll
        for (int c = 0; c < NCLS; ++c) blog[j][c] = 0.f;
    const float4* W4 = reinterpret_cast<const float4*>(W);
    for (int it = 0; it < 3; ++it) {
        if (it > 0) {
            for (int c = 0; c < NCLS; ++c) {
                float vp[KDO];
                #pragma unroll
                for (int d = 0; d < KDO; ++d) vp[d] = v_prev[c * KDO + d];
                #pragma unroll
                for (int j = 0; j < 5; ++j) {
                    int i = t + 256 * j;
                    if (i < NCAPS) {
                        size_t wb = (size_t)(c * NCAPS + i) * 32;
                        float a = 0.f;
                        #pragma unroll
                        for (int d = 0; d < KDO; ++d) {
                            float4 w0 = W4[wb + 2 * d]; float4 w1 = W4[wb + 2 * d + 1];
                            float u = w0.x*xr[j][0].x + w0.y*xr[j][0].y + w0.z*xr[j][0].z
                                    + w0.w*xr[j][0].w + w1.x*xr[j][1].x + w1.y*xr[j][1].y
                                    + w1.z*xr[j][1].z + w1.w*xr[j][1].w;
                            a += u * vp[d];
                        }
                        blog[j][c] += a;
                    }
                }
            }
        }
        float sm2[5], sid2[5];
        #pragma unroll
        for (int j = 0; j < 5; ++j) {
            int i = t + 256 * j;
            if (i < NCAPS) {
                float m = blog[j][0];
                #pragma unroll
                for (int c = 1; c < NCLS; ++c) m = fmaxf(m, blog[j][c]);
                float den = 0.f;
                #pragma unroll
                for (int c = 0; c < NCLS; ++c) den += __expf(blog[j][c] - m);
                sm2[j] = m; sid2[j] = 1.f / den;
            }
        }
        for (int c = 0; c < NCLS; ++c) {
            float acc[KDO];
            #pragma unroll
            for (int d = 0; d < KDO; ++d) acc[d] = 0.f;
            #pragma unroll
            for (int j = 0; j < 5; ++j) {
                int i = t + 256 * j;
                if (i < NCAPS) {
                    float w = __expf(blog[j][c] - sm2[j]) * sid2[j];
                    size_t wb = (size_t)(c * NCAPS + i) * 32;
                    #pragma unroll
                    for (int d = 0; d < KDO; ++d) {
                        float4 w0 = W4[wb + 2 * d]; float4 w1 = W4[wb + 2 * d + 1];
                        float u = w0.x*xr[j][0].x + w0.y*xr[j][0].y + w0.z*xr[j][0].z
                                + w0.w*xr[j][0].w + w1.x*xr[j][1].x + w1.y*xr[j][1].y
                                + w1.z*xr[j][1].z + w1.w*xr[j][1].w;
                        acc[d] += w * u;
                    }
                }
            }
            #pragma unroll
            for (int d = 0; d < KDO; ++d) {
                float v = acc[d];
                v += __shfl_xor(v, 32, 64); v += __shfl_xor(v, 16, 64);
                v += __shfl_xor(v,  8, 64); v += __shfl_xor(v,  4, 64);
                v += __shfl_xor(v,  2, 64); v += __shfl_xor(v,  1, 64);
                if (lane == 0) redf[(c * 4 + wave) * KDO + d] = v;
            }
        }
        __syncthreads();
        if (t < NCLS * KDO) {
            int c = t >> 4, d = t & 15;
            float s = redf[(c*4+0)*KDO+d] + redf[(c*4+1)*KDO+d]
                    + redf[(c*4+2)*KDO+d] + redf[(c*4+3)*KDO+d];
            float nsq = s * s;
            nsq += __shfl_xor(nsq, 8, 16); nsq += __shfl_xor(nsq, 4, 16);
            nsq += __shfl_xor(nsq, 2, 16); nsq += __shfl_xor(nsq, 1, 16);
            float scale = sqrtf(nsq) / (1.f + nsq);
            float vv = s * scale;
            v_prev[t] = vv;
            if (it == 2) out[(size_t)b * NCLS * KDO + t] = vv;
        }
        __syncthreads();
    }
}

extern "C" void kernel_launch(void* const* d_in, const int* in_sizes, int n_in,
                              void* d_out, int out_size, void* d_ws, size_t ws_size,
                              hipStream_t stream) {
    const float* x = (const float*)d_in[0];              // [256, 1152, 8] fp32
    const float4* W4 = (const float4*)d_in[1];           // [10, 1152, 1, 16, 8] fp32
    float* out = (float*)d_out;                          // [256, 10, 1, 16] fp32
    (void)in_sizes; (void)n_in; (void)out_size;

    const size_t WT = (size_t)NCLS * KDO * NCAPS * sizeof(u4);       //  2.95 MB
    const size_t UT = (size_t)NB * NCLS * 2 * NCAPS * sizeof(u4);    // 94.37 MB
    const size_t BL = (size_t)NB * NCLS * NCAPS * sizeof(float);     // 11.80 MB
    const size_t SB = (size_t)NB * NCLS * KDO * sizeof(float);       //  160 KB
    const size_t VP = (size_t)NB * NCLS * 8 * sizeof(unsigned);      //   80 KB
    const size_t need = WT + UT + BL + 3 * SB + 2 * VP;              // ~109.9 MB

    if (ws_size >= need) {
        char* p = (char*)d_ws;
        u4* Wt       = (u4*)p;        p += WT;
        u4* ut       = (u4*)p;        p += UT;
        float* blog  = (float*)p;     p += BL;
        float* s0    = (float*)p;     p += SB;
        float* s1    = (float*)p;     p += SB;
        float* s2    = (float*)p;     p += SB;
        unsigned* v0 = (unsigned*)p;  p += VP;
        unsigned* v1 = (unsigned*)p;

        hipMemsetAsync(s0, 0, 3 * SB, stream);           // zero s0,s1,s2 (contiguous)

        int total = NCLS * NCAPS * KDO;
        pack_W_f16<<<dim3((total + 255) / 256), dim3(256), 0, stream>>>(W4, Wt);
        k_uhat_s0<<<dim3(NCH, NB, NCLS / 2), dim3(CHUNK), 0, stream>>>(Wt, x, ut, s0);
        k_squash<<<dim3(NB * NCLS / 4), dim3(256), 0, stream>>>(s0, 0.1f, v0, out, 0);
        k_route<<<dim3(NCH, NB), dim3(CHUNK), 0, stream>>>(ut, v0, blog, s1, 1, 1);
        k_squash<<<dim3(NB * NCLS / 4), dim3(256), 0, stream>>>(s1, 1.f, v1, out, 0);
        k_route<<<dim3(NCH, NB), dim3(CHUNK), 0, stream>>>(ut, v1, blog, s2, 0, 0);
        k_squash<<<dim3(NB * NCLS / 4), dim3(256), 0, stream>>>(s2, 1.f, v0, out, 1);
    } else {
        caps_routing_fb<<<dim3(NB), dim3(256), 0, stream>>>(x, (const float*)d_in[1], out);
    }
}

// Round 16
// 259.885 us; speedup vs baseline: 1.5289x; 1.4454x over previous
//
#include <hip/hip_runtime.h>

// DigitCapsules dynamic routing. Round-16: shuffle-free streaming split.
//  - R15 diagnosis: both hot kernels were DS-pipe-bound on wave-shuffle
//    reduction trees (k_route: 960 ds_bpermute/thread vs 20 loads;
//    k_uhat_s0: 192/thread — and 5x block parallelism moved nothing).
//  - Fix: give the s-reduction its own kernel with the right shape.
//      k_uhat   : thread=capsule, 2 classes (grid z): compute ut ONLY.
//                 Pure stream: 32 loads, 128 fdot2, 4 stores. No DS ops.
//      k_sv     : block=(b,c) [2560 blocks, 256 thr]: s = sum_i w_i * u_i
//                 (w=1, scale=0.1 for it0), ONE block reduction (96 shfl),
//                 squash fused in-block -> v packed f16 (or final out).
//      k_logits : thread=capsule: u for all 10 classes in 80 VGPRs (static
//                 unroll), agreement + blog + softmax -> w stored f16.
//                 Zero shuffles, zero atomics.
//  - No atomics anywhere -> no memsets. 7 dispatches total.
//  - Proven pieces: f16 Wt[c][d][i] + v_dot2_f32_f16 (absmax 0.0039),
//    ut[b][c][h][i] u4 (16 B lane stride), it0 softmax(0)=0.1 shortcut,
//    full static unrolling wherever a register array is indexed.

#define NCLS   10
#define NCAPS  1152
#define KDO    16
#define CHUNK  128
#define NCH    9           // 1152 / 128
#define NB     256

typedef _Float16 h2_t __attribute__((ext_vector_type(2)));
typedef unsigned u4 __attribute__((ext_vector_type(4)));

static __device__ __forceinline__ unsigned pack2h(float a, float b) {
    union { _Float16 h[2]; unsigned u; } p;
    p.h[0] = (_Float16)a;
    p.h[1] = (_Float16)b;
    return p.u;
}

static __device__ __forceinline__ float dot8h(u4 r, const unsigned* xh) {
    union { unsigned u; h2_t h; } w0, w1, w2, w3, a0, a1, a2, a3;
    w0.u = r.x; w1.u = r.y; w2.u = r.z; w3.u = r.w;
    a0.u = xh[0]; a1.u = xh[1]; a2.u = xh[2]; a3.u = xh[3];
#if __has_builtin(__builtin_amdgcn_fdot2)
    float acc = __builtin_amdgcn_fdot2(w0.h, a0.h, 0.f, false);
    acc = __builtin_amdgcn_fdot2(w1.h, a1.h, acc, false);
    acc = __builtin_amdgcn_fdot2(w2.h, a2.h, acc, false);
    acc = __builtin_amdgcn_fdot2(w3.h, a3.h, acc, false);
    return acc;
#else
    return (float)w0.h.x * (float)a0.h.x + (float)w0.h.y * (float)a0.h.y
         + (float)w1.h.x * (float)a1.h.x + (float)w1.h.y * (float)a1.h.y
         + (float)w2.h.x * (float)a2.h.x + (float)w2.h.y * (float)a2.h.y
         + (float)w3.h.x * (float)a3.h.x + (float)w3.h.y * (float)a3.h.y;
#endif
}

static __device__ __forceinline__ float dot2h(unsigned a, unsigned b, float acc) {
    union { unsigned u; h2_t h; } pa, pb;
    pa.u = a; pb.u = b;
#if __has_builtin(__builtin_amdgcn_fdot2)
    return __builtin_amdgcn_fdot2(pa.h, pb.h, acc, false);
#else
    return acc + (float)pa.h.x * (float)pb.h.x + (float)pa.h.y * (float)pb.h.y;
#endif
}

static __device__ __forceinline__ float wave_sum(float v) {
    v += __shfl_xor(v, 32, 64);
    v += __shfl_xor(v, 16, 64);
    v += __shfl_xor(v,  8, 64);
    v += __shfl_xor(v,  4, 64);
    v += __shfl_xor(v,  2, 64);
    v += __shfl_xor(v,  1, 64);
    return v;
}

// Wt[c][d][i] : u4 holding f16 W[c,i,0,d,k] for k=0..7
__global__ __launch_bounds__(256)
void pack_W_f16(const float4* __restrict__ W4, u4* __restrict__ Wt) {
    int tid = blockIdx.x * blockDim.x + threadIdx.x;   // (c*NCAPS+i)*KDO + d
    if (tid >= NCLS * NCAPS * KDO) return;
    int d = tid & 15;
    int rest = tid >> 4;
    int i = rest % NCAPS;
    int c = rest / NCAPS;
    float4 a = W4[2 * tid];
    float4 b = W4[2 * tid + 1];
    u4 o;
    o.x = pack2h(a.x, a.y);
    o.y = pack2h(a.z, a.w);
    o.z = pack2h(b.x, b.y);
    o.w = pack2h(b.z, b.w);
    Wt[(size_t)(c * KDO + d) * NCAPS + i] = o;
}

// ---- phase 1: ut only. grid (NCH, NB, 5): 2 classes/block. Pure stream. ----
__global__ __launch_bounds__(CHUNK, 1)
void k_uhat(const u4* __restrict__ Wt, const float* __restrict__ x,
            u4* __restrict__ ut)
{
    const int t  = threadIdx.x;
    const int ii = blockIdx.x * CHUNK + t;
    const int b  = blockIdx.y;
    const int c0 = blockIdx.z * 2;

    const float4* x4 = reinterpret_cast<const float4*>(x) + (size_t)b * NCAPS * 2;
    float4 x0 = x4[2 * ii];
    float4 x1 = x4[2 * ii + 1];
    unsigned xh[4] = { pack2h(x0.x, x0.y), pack2h(x0.z, x0.w),
                       pack2h(x1.x, x1.y), pack2h(x1.z, x1.w) };
    u4* utb = ut + (size_t)b * NCLS * 2 * NCAPS;

    u4 r[2][KDO];                                  // all 32 loads in flight
    #pragma unroll
    for (int cc = 0; cc < 2; ++cc) {
        const u4* base = Wt + (size_t)(c0 + cc) * KDO * NCAPS + ii;
        #pragma unroll
        for (int d = 0; d < KDO; ++d)
            r[cc][d] = __builtin_nontemporal_load(base + (size_t)d * NCAPS);
    }
    #pragma unroll
    for (int cc = 0; cc < 2; ++cc) {
        const int c = c0 + cc;
        u4 h0, h1;
        #pragma unroll
        for (int dp = 0; dp < 8; ++dp) {
            float u0 = dot8h(r[cc][2 * dp],     xh);
            float u1 = dot8h(r[cc][2 * dp + 1], xh);
            unsigned pk = pack2h(u0, u1);
            if (dp < 4) ((unsigned*)&h0)[dp] = pk;
            else        ((unsigned*)&h1)[dp - 4] = pk;
        }
        utb[((size_t)c * 2 + 0) * NCAPS + ii] = h0;
        utb[((size_t)c * 2 + 1) * NCAPS + ii] = h1;
    }
}

// ---- phase 2: s = sum_i w_i * u_i, block reduce, squash. block=(b,c). ----
__global__ __launch_bounds__(256, 1)
void k_sv(const u4* __restrict__ ut, const unsigned short* __restrict__ w,
          float scale, unsigned* __restrict__ vph, float* __restrict__ out,
          int last)
{
    __shared__ float red[4][KDO];
    const int gw   = blockIdx.x;                   // b*NCLS + c
    const int t    = threadIdx.x;
    const int lane = t & 63;
    const int wave = t >> 6;

    const u4* utr = ut + (size_t)gw * 2 * NCAPS;   // [half][i]
    const unsigned short* wr = w ? w + (size_t)gw * NCAPS : nullptr;

    float acc[KDO];
    #pragma unroll
    for (int d = 0; d < KDO; ++d) acc[d] = 0.f;

    #pragma unroll
    for (int j = 0; j < 5; ++j) {
        int i = t + 256 * j;
        if (i < NCAPS) {
            u4 h0 = utr[i];
            u4 h1 = utr[NCAPS + i];
            float wgt = wr ? (float)*reinterpret_cast<const _Float16*>(wr + i) : 1.f;
            #pragma unroll
            for (int dp = 0; dp < 8; ++dp) {
                union { unsigned u; h2_t h; } p;
                p.u = (dp < 4) ? ((const unsigned*)&h0)[dp]
                               : ((const unsigned*)&h1)[dp - 4];
                acc[2 * dp]     += wgt * (float)p.h.x;
                acc[2 * dp + 1] += wgt * (float)p.h.y;
            }
        }
    }

    #pragma unroll
    for (int d = 0; d < KDO; ++d) {                // ONE block reduction
        float v = wave_sum(acc[d]);
        if (lane == 0) red[wave][d] = v;
    }
    __syncthreads();

    if (wave == 0) {                               // fused squash
        float s = 0.f;
        if (lane < KDO)
            s = (red[0][lane] + red[1][lane] + red[2][lane] + red[3][lane]) * scale;
        float nsq = s * s;
        nsq += __shfl_xor(nsq, 8, 16);
        nsq += __shfl_xor(nsq, 4, 16);
        nsq += __shfl_xor(nsq, 2, 16);
        nsq += __shfl_xor(nsq, 1, 16);
        float sc = sqrtf(nsq) / (1.f + nsq);       // (nsq/(1+nsq))/sqrt(nsq)
        float vv = s * sc;
        if (last) {
            if (lane < KDO) out[(size_t)gw * KDO + lane] = vv;
        } else {
            float a = __shfl(vv, 2 * (lane & 7), 64);
            float b = __shfl(vv, 2 * (lane & 7) + 1, 64);
            if (lane < 8) vph[(size_t)gw * 8 + lane] = pack2h(a, b);
        }
    }
}

// ---- phase 3: agreement + blog + softmax -> w (f16). Zero shuffles. ----
__global__ __launch_bounds__(CHUNK, 1)
void k_logits(const u4* __restrict__ ut, const unsigned* __restrict__ vph,
              float* __restrict__ blog, unsigned short* __restrict__ w,
              int first)
{
    __shared__ unsigned vsh[NCLS * 8];
    const int t  = threadIdx.x;
    const int ii = blockIdx.x * CHUNK + t;
    const int b  = blockIdx.y;

    if (t < NCLS * 8) vsh[t] = vph[(size_t)b * NCLS * 8 + t];
    __syncthreads();

    const u4* utb = ut + (size_t)b * NCLS * 2 * NCAPS;
    float* blogb = blog + (size_t)b * NCLS * NCAPS;
    unsigned short* wb = w + (size_t)b * NCLS * NCAPS;

    u4 up0[NCLS], up1[NCLS];                       // 80 VGPRs, static idx only
    #pragma unroll
    for (int c = 0; c < NCLS; ++c) {
        up0[c] = utb[((size_t)c * 2 + 0) * NCAPS + ii];
        up1[c] = utb[((size_t)c * 2 + 1) * NCAPS + ii];
    }

    float bl[NCLS];
    #pragma unroll
    for (int c = 0; c < NCLS; ++c) {
        float a = first ? 0.f : blogb[(size_t)c * NCAPS + ii];
        #pragma unroll
        for (int dp = 0; dp < 4; ++dp)
            a = dot2h(((const unsigned*)&up0[c])[dp], vsh[c * 8 + dp], a);
        #pragma unroll
        for (int dp = 0; dp < 4; ++dp)
            a = dot2h(((const unsigned*)&up1[c])[dp], vsh[c * 8 + 4 + dp], a);
        bl[c] = a;
        if (first) blogb[(size_t)c * NCAPS + ii] = a;  // only it1's blog is re-read
    }

    float m = bl[0];
    #pragma unroll
    for (int c = 1; c < NCLS; ++c) m = fmaxf(m, bl[c]);
    float den = 0.f;
    #pragma unroll
    for (int c = 0; c < NCLS; ++c) den += __expf(bl[c] - m);
    float sid = 1.f / den;

    #pragma unroll
    for (int c = 0; c < NCLS; ++c) {
        union { _Float16 h; unsigned short s; } q;
        q.h = (_Float16)(__expf(bl[c] - m) * sid);
        wb[(size_t)c * NCAPS + ii] = q.s;          // coalesced within each c
    }
}

// ---- fallback (small ws): round-1 fp32 fused kernel, proven correct ----
__global__ __launch_bounds__(256, 2)
void caps_routing_fb(const float* __restrict__ x, const float* __restrict__ W,
                     float* __restrict__ out)
{
    const int b    = blockIdx.x;
    const int t    = threadIdx.x;
    const int lane = t & 63;
    const int wave = t >> 6;
    __shared__ float v_prev[NCLS * KDO];
    __shared__ float redf[NCLS * 4 * KDO];
    float4 xr[5][2];
    const float4* x4 = reinterpret_cast<const float4*>(x + (size_t)b * NCAPS * 8);
    #pragma unroll
    for (int j = 0; j < 5; ++j) {
        int i = t + 256 * j;
        if (i < NCAPS) { xr[j][0] = x4[2 * i]; xr[j][1] = x4[2 * i + 1]; }
    }
    float blog[5][NCLS];
    #pragma unroll
    for (int j = 0; j < 5; ++j)
        #pragma unroll
        for (int c = 0; c < NCLS; ++c) blog[j][c] = 0.f;
    const float4* W4 = reinterpret_cast<const float4*>(W);
    for (int it = 0; it < 3; ++it) {
        if (it > 0) {
            for (int c = 0; c < NCLS; ++c) {
                float vp[KDO];
                #pragma unroll
                for (int d = 0; d < KDO; ++d) vp[d] = v_prev[c * KDO + d];
                #pragma unroll
                for (int j = 0; j < 5; ++j) {
                    int i = t + 256 * j;
                    if (i < NCAPS) {
                        size_t wbx = (size_t)(c * NCAPS + i) * 32;
                        float a = 0.f;
                        #pragma unroll
                        for (int d = 0; d < KDO; ++d) {
                            float4 w0 = W4[wbx + 2 * d]; float4 w1 = W4[wbx + 2 * d + 1];
                            float u = w0.x*xr[j][0].x + w0.y*xr[j][0].y + w0.z*xr[j][0].z
                                    + w0.w*xr[j][0].w + w1.x*xr[j][1].x + w1.y*xr[j][1].y
                                    + w1.z*xr[j][1].z + w1.w*xr[j][1].w;
                            a += u * vp[d];
                        }
                        blog[j][c] += a;
                    }
                }
            }
        }
        float sm2[5], sid2[5];
        #pragma unroll
        for (int j = 0; j < 5; ++j) {
            int i = t + 256 * j;
            if (i < NCAPS) {
                float m = blog[j][0];
                #pragma unroll
                for (int c = 1; c < NCLS; ++c) m = fmaxf(m, blog[j][c]);
                float den = 0.f;
                #pragma unroll
                for (int c = 0; c < NCLS; ++c) den += __expf(blog[j][c] - m);
                sm2[j] = m; sid2[j] = 1.f / den;
            }
        }
        for (int c = 0; c < NCLS; ++c) {
            float acc[KDO];
            #pragma unroll
            for (int d = 0; d < KDO; ++d) acc[d] = 0.f;
            #pragma unroll
            for (int j = 0; j < 5; ++j) {
                int i = t + 256 * j;
                if (i < NCAPS) {
                    float wq = __expf(blog[j][c] - sm2[j]) * sid2[j];
                    size_t wbx = (size_t)(c * NCAPS + i) * 32;
                    #pragma unroll
                    for (int d = 0; d < KDO; ++d) {
                        float4 w0 = W4[wbx + 2 * d]; float4 w1 = W4[wbx + 2 * d + 1];
                        float u = w0.x*xr[j][0].x + w0.y*xr[j][0].y + w0.z*xr[j][0].z
                                + w0.w*xr[j][0].w + w1.x*xr[j][1].x + w1.y*xr[j][1].y
                                + w1.z*xr[j][1].z + w1.w*xr[j][1].w;
                        acc[d] += wq * u;
                    }
                }
            }
            #pragma unroll
            for (int d = 0; d < KDO; ++d) {
                float v = acc[d];
                v += __shfl_xor(v, 32, 64); v += __shfl_xor(v, 16, 64);
                v += __shfl_xor(v,  8, 64); v += __shfl_xor(v,  4, 64);
                v += __shfl_xor(v,  2, 64); v += __shfl_xor(v,  1, 64);
                if (lane == 0) redf[(c * 4 + wave) * KDO + d] = v;
            }
        }
        __syncthreads();
        if (t < NCLS * KDO) {
            int c = t >> 4, d = t & 15;
            float s = redf[(c*4+0)*KDO+d] + redf[(c*4+1)*KDO+d]
                    + redf[(c*4+2)*KDO+d] + redf[(c*4+3)*KDO+d];
            float nsq = s * s;
            nsq += __shfl_xor(nsq, 8, 16); nsq += __shfl_xor(nsq, 4, 16);
            nsq += __shfl_xor(nsq, 2, 16); nsq += __shfl_xor(nsq, 1, 16);
            float scale = sqrtf(nsq) / (1.f + nsq);
            float vv = s * scale;
            v_prev[t] = vv;
            if (it == 2) out[(size_t)b * NCLS * KDO + t] = vv;
        }
        __syncthreads();
    }
}

extern "C" void kernel_launch(void* const* d_in, const int* in_sizes, int n_in,
                              void* d_out, int out_size, void* d_ws, size_t ws_size,
                              hipStream_t stream) {
    const float* x = (const float*)d_in[0];              // [256, 1152, 8] fp32
    const float4* W4 = (const float4*)d_in[1];           // [10, 1152, 1, 16, 8] fp32
    float* out = (float*)d_out;                          // [256, 10, 1, 16] fp32
    (void)in_sizes; (void)n_in; (void)out_size;

    const size_t WT = (size_t)NCLS * KDO * NCAPS * sizeof(u4);            //  2.95 MB
    const size_t UT = (size_t)NB * NCLS * 2 * NCAPS * sizeof(u4);         // 94.37 MB
    const size_t BL = (size_t)NB * NCLS * NCAPS * sizeof(float);          // 11.80 MB
    const size_t WB = (size_t)NB * NCLS * NCAPS * sizeof(unsigned short); //  5.90 MB
    const size_t VP = (size_t)NB * NCLS * 8 * sizeof(unsigned);           //   80 KB
    const size_t need = WT + UT + BL + WB + 2 * VP;                       // ~115.2 MB

    if (ws_size >= need) {
        char* p = (char*)d_ws;
        u4* Wt             = (u4*)p;             p += WT;
        u4* ut             = (u4*)p;             p += UT;
        float* blog        = (float*)p;          p += BL;
        unsigned short* wb = (unsigned short*)p; p += WB;
        unsigned* v0       = (unsigned*)p;       p += VP;
        unsigned* v1       = (unsigned*)p;

        int total = NCLS * NCAPS * KDO;
        pack_W_f16<<<dim3((total + 255) / 256), dim3(256), 0, stream>>>(W4, Wt);
        k_uhat<<<dim3(NCH, NB, NCLS / 2), dim3(CHUNK), 0, stream>>>(Wt, x, ut);
        k_sv<<<dim3(NB * NCLS), dim3(256), 0, stream>>>(ut, nullptr, 0.1f, v0, out, 0);
        k_logits<<<dim3(NCH, NB), dim3(CHUNK), 0, stream>>>(ut, v0, blog, wb, 1);
        k_sv<<<dim3(NB * NCLS), dim3(256), 0, stream>>>(ut, wb, 1.f, v1, out, 0);
        k_logits<<<dim3(NCH, NB), dim3(CHUNK), 0, stream>>>(ut, v1, blog, wb, 0);
        k_sv<<<dim3(NB * NCLS), dim3(256), 0, stream>>>(ut, wb, 1.f, v0, out, 1);
    } else {
        caps_routing_fb<<<dim3(NB), dim3(256), 0, stream>>>(x, (const float*)d_in[1], out);
    }
}

// Round 17
// 218.744 us; speedup vs baseline: 1.8164x; 1.1881x over previous
//
#include <hip/hip_runtime.h>

// DigitCapsules dynamic routing. Round-17 = Round-16 split + b-batched k_uhat.
//  - R16: k_uhat (95 us, 61% occ, VALU 10.7%) obeys the per-CU law
//    (~73 cyc/wave-mem-instr): 3420 instr/CU ~ 104 us. Dominated by W
//    re-reads (every b re-streams W: 755 MB logical).
//  - FIX: 4 batches per block. One W load set (2 classes x 16 rows) feeds
//    dots for 4 x's -> W logical 755 -> 189 MB; per-b mem instr 38 -> 13.
//    Predicted k_uhat ~35-45 us.
//  - x pre-packed to f16 u4 once (pack_x_f16): k_uhat reads 1 u4 per b.
//  - k_sv / k_logits / fallback unchanged from R16 (passed, near floors).

#define NCLS   10
#define NCAPS  1152
#define KDO    16
#define CHUNK  128
#define NCH    9           // 1152 / 128
#define NB     256
#define BBAT   4           // batches per k_uhat block

typedef _Float16 h2_t __attribute__((ext_vector_type(2)));
typedef unsigned u4 __attribute__((ext_vector_type(4)));

static __device__ __forceinline__ unsigned pack2h(float a, float b) {
    union { _Float16 h[2]; unsigned u; } p;
    p.h[0] = (_Float16)a;
    p.h[1] = (_Float16)b;
    return p.u;
}

static __device__ __forceinline__ float dot8h(u4 r, const unsigned* xh) {
    union { unsigned u; h2_t h; } w0, w1, w2, w3, a0, a1, a2, a3;
    w0.u = r.x; w1.u = r.y; w2.u = r.z; w3.u = r.w;
    a0.u = xh[0]; a1.u = xh[1]; a2.u = xh[2]; a3.u = xh[3];
#if __has_builtin(__builtin_amdgcn_fdot2)
    float acc = __builtin_amdgcn_fdot2(w0.h, a0.h, 0.f, false);
    acc = __builtin_amdgcn_fdot2(w1.h, a1.h, acc, false);
    acc = __builtin_amdgcn_fdot2(w2.h, a2.h, acc, false);
    acc = __builtin_amdgcn_fdot2(w3.h, a3.h, acc, false);
    return acc;
#else
    return (float)w0.h.x * (float)a0.h.x + (float)w0.h.y * (float)a0.h.y
         + (float)w1.h.x * (float)a1.h.x + (float)w1.h.y * (float)a1.h.y
         + (float)w2.h.x * (float)a2.h.x + (float)w2.h.y * (float)a2.h.y
         + (float)w3.h.x * (float)a3.h.x + (float)w3.h.y * (float)a3.h.y;
#endif
}

static __device__ __forceinline__ float dot2h(unsigned a, unsigned b, float acc) {
    union { unsigned u; h2_t h; } pa, pb;
    pa.u = a; pb.u = b;
#if __has_builtin(__builtin_amdgcn_fdot2)
    return __builtin_amdgcn_fdot2(pa.h, pb.h, acc, false);
#else
    return acc + (float)pa.h.x * (float)pb.h.x + (float)pa.h.y * (float)pb.h.y;
#endif
}

static __device__ __forceinline__ float wave_sum(float v) {
    v += __shfl_xor(v, 32, 64);
    v += __shfl_xor(v, 16, 64);
    v += __shfl_xor(v,  8, 64);
    v += __shfl_xor(v,  4, 64);
    v += __shfl_xor(v,  2, 64);
    v += __shfl_xor(v,  1, 64);
    return v;
}

// Wt[c][d][i] : u4 holding f16 W[c,i,0,d,k] for k=0..7
__global__ __launch_bounds__(256)
void pack_W_f16(const float4* __restrict__ W4, u4* __restrict__ Wt) {
    int tid = blockIdx.x * blockDim.x + threadIdx.x;   // (c*NCAPS+i)*KDO + d
    if (tid >= NCLS * NCAPS * KDO) return;
    int d = tid & 15;
    int rest = tid >> 4;
    int i = rest % NCAPS;
    int c = rest / NCAPS;
    float4 a = W4[2 * tid];
    float4 b = W4[2 * tid + 1];
    u4 o;
    o.x = pack2h(a.x, a.y);
    o.y = pack2h(a.z, a.w);
    o.z = pack2h(b.x, b.y);
    o.w = pack2h(b.z, b.w);
    Wt[(size_t)(c * KDO + d) * NCAPS + i] = o;
}

// xp[b][i] : u4 of 8 f16 (the capsule's 8 inputs)
__global__ __launch_bounds__(256)
void pack_x_f16(const float4* __restrict__ x4, u4* __restrict__ xp) {
    int tid = blockIdx.x * blockDim.x + threadIdx.x;   // b*NCAPS + i
    if (tid >= NB * NCAPS) return;
    float4 a = x4[2 * tid];
    float4 b = x4[2 * tid + 1];
    u4 o;
    o.x = pack2h(a.x, a.y);
    o.y = pack2h(a.z, a.w);
    o.z = pack2h(b.x, b.y);
    o.w = pack2h(b.z, b.w);
    xp[tid] = o;
}

// ---- phase 1: ut. grid (NCH, NB/4, 5): 2 classes x 4 batches per block. ----
__global__ __launch_bounds__(CHUNK, 1)
void k_uhat(const u4* __restrict__ Wt, const u4* __restrict__ xp,
            u4* __restrict__ ut)
{
    const int t  = threadIdx.x;
    const int ii = blockIdx.x * CHUNK + t;
    const int b0 = blockIdx.y * BBAT;
    const int c0 = blockIdx.z * 2;

    u4 xq[BBAT];
    #pragma unroll
    for (int k = 0; k < BBAT; ++k)
        xq[k] = xp[(size_t)(b0 + k) * NCAPS + ii];

    #pragma unroll
    for (int cc = 0; cc < 2; ++cc) {
        const int c = c0 + cc;
        const u4* base = Wt + (size_t)c * KDO * NCAPS + ii;
        u4 r[KDO];                                 // 16 loads in flight
        #pragma unroll
        for (int d = 0; d < KDO; ++d)
            r[d] = __builtin_nontemporal_load(base + (size_t)d * NCAPS);

        #pragma unroll
        for (int k = 0; k < BBAT; ++k) {           // reuse W for 4 batches
            const unsigned* xh = (const unsigned*)&xq[k];
            u4 h0, h1;
            #pragma unroll
            for (int dp = 0; dp < 8; ++dp) {
                float u0 = dot8h(r[2 * dp],     xh);
                float u1 = dot8h(r[2 * dp + 1], xh);
                unsigned pk = pack2h(u0, u1);
                if (dp < 4) ((unsigned*)&h0)[dp] = pk;
                else        ((unsigned*)&h1)[dp - 4] = pk;
            }
            u4* utb = ut + (size_t)(b0 + k) * NCLS * 2 * NCAPS;
            utb[((size_t)c * 2 + 0) * NCAPS + ii] = h0;
            utb[((size_t)c * 2 + 1) * NCAPS + ii] = h1;
        }
    }
}

// ---- phase 2: s = sum_i w_i * u_i, block reduce, squash. block=(b,c). ----
__global__ __launch_bounds__(256, 1)
void k_sv(const u4* __restrict__ ut, const unsigned short* __restrict__ w,
          float scale, unsigned* __restrict__ vph, float* __restrict__ out,
          int last)
{
    __shared__ float red[4][KDO];
    const int gw   = blockIdx.x;                   // b*NCLS + c
    const int t    = threadIdx.x;
    const int lane = t & 63;
    const int wave = t >> 6;

    const u4* utr = ut + (size_t)gw * 2 * NCAPS;   // [half][i]
    const unsigned short* wr = w ? w + (size_t)gw * NCAPS : nullptr;

    float acc[KDO];
    #pragma unroll
    for (int d = 0; d < KDO; ++d) acc[d] = 0.f;

    #pragma unroll
    for (int j = 0; j < 5; ++j) {
        int i = t + 256 * j;
        if (i < NCAPS) {
            u4 h0 = utr[i];
            u4 h1 = utr[NCAPS + i];
            float wgt = wr ? (float)*reinterpret_cast<const _Float16*>(wr + i) : 1.f;
            #pragma unroll
            for (int dp = 0; dp < 8; ++dp) {
                union { unsigned u; h2_t h; } p;
                p.u = (dp < 4) ? ((const unsigned*)&h0)[dp]
                               : ((const unsigned*)&h1)[dp - 4];
                acc[2 * dp]     += wgt * (float)p.h.x;
                acc[2 * dp + 1] += wgt * (float)p.h.y;
            }
        }
    }

    #pragma unroll
    for (int d = 0; d < KDO; ++d) {                // ONE block reduction
        float v = wave_sum(acc[d]);
        if (lane == 0) red[wave][d] = v;
    }
    __syncthreads();

    if (wave == 0) {                               // fused squash
        float s = 0.f;
        if (lane < KDO)
            s = (red[0][lane] + red[1][lane] + red[2][lane] + red[3][lane]) * scale;
        float nsq = s * s;
        nsq += __shfl_xor(nsq, 8, 16);
        nsq += __shfl_xor(nsq, 4, 16);
        nsq += __shfl_xor(nsq, 2, 16);
        nsq += __shfl_xor(nsq, 1, 16);
        float sc = sqrtf(nsq) / (1.f + nsq);       // (nsq/(1+nsq))/sqrt(nsq)
        float vv = s * sc;
        if (last) {
            if (lane < KDO) out[(size_t)gw * KDO + lane] = vv;
        } else {
            float a = __shfl(vv, 2 * (lane & 7), 64);
            float b = __shfl(vv, 2 * (lane & 7) + 1, 64);
            if (lane < 8) vph[(size_t)gw * 8 + lane] = pack2h(a, b);
        }
    }
}

// ---- phase 3: agreement + blog + softmax -> w (f16). Zero shuffles. ----
__global__ __launch_bounds__(CHUNK, 1)
void k_logits(const u4* __restrict__ ut, const unsigned* __restrict__ vph,
              float* __restrict__ blog, unsigned short* __restrict__ w,
              int first)
{
    __shared__ unsigned vsh[NCLS * 8];
    const int t  = threadIdx.x;
    const int ii = blockIdx.x * CHUNK + t;
    const int b  = blockIdx.y;

    if (t < NCLS * 8) vsh[t] = vph[(size_t)b * NCLS * 8 + t];
    __syncthreads();

    const u4* utb = ut + (size_t)b * NCLS * 2 * NCAPS;
    float* blogb = blog + (size_t)b * NCLS * NCAPS;
    unsigned short* wb = w + (size_t)b * NCLS * NCAPS;

    u4 up0[NCLS], up1[NCLS];                       // 80 VGPRs, static idx only
    #pragma unroll
    for (int c = 0; c < NCLS; ++c) {
        up0[c] = utb[((size_t)c * 2 + 0) * NCAPS + ii];
        up1[c] = utb[((size_t)c * 2 + 1) * NCAPS + ii];
    }

    float bl[NCLS];
    #pragma unroll
    for (int c = 0; c < NCLS; ++c) {
        float a = first ? 0.f : blogb[(size_t)c * NCAPS + ii];
        #pragma unroll
        for (int dp = 0; dp < 4; ++dp)
            a = dot2h(((const unsigned*)&up0[c])[dp], vsh[c * 8 + dp], a);
        #pragma unroll
        for (int dp = 0; dp < 4; ++dp)
            a = dot2h(((const unsigned*)&up1[c])[dp], vsh[c * 8 + 4 + dp], a);
        bl[c] = a;
        if (first) blogb[(size_t)c * NCAPS + ii] = a;  // only it1's blog is re-read
    }

    float m = bl[0];
    #pragma unroll
    for (int c = 1; c < NCLS; ++c) m = fmaxf(m, bl[c]);
    float den = 0.f;
    #pragma unroll
    for (int c = 0; c < NCLS; ++c) den += __expf(bl[c] - m);
    float sid = 1.f / den;

    #pragma unroll
    for (int c = 0; c < NCLS; ++c) {
        union { _Float16 h; unsigned short s; } q;
        q.h = (_Float16)(__expf(bl[c] - m) * sid);
        wb[(size_t)c * NCAPS + ii] = q.s;          // coalesced within each c
    }
}

// ---- fallback (small ws): round-1 fp32 fused kernel, proven correct ----
__global__ __launch_bounds__(256, 2)
void caps_routing_fb(const float* __restrict__ x, const float* __restrict__ W,
                     float* __restrict__ out)
{
    const int b    = blockIdx.x;
    const int t    = threadIdx.x;
    const int lane = t & 63;
    const int wave = t >> 6;
    __shared__ float v_prev[NCLS * KDO];
    __shared__ float redf[NCLS * 4 * KDO];
    float4 xr[5][2];
    const float4* x4 = reinterpret_cast<const float4*>(x + (size_t)b * NCAPS * 8);
    #pragma unroll
    for (int j = 0; j < 5; ++j) {
        int i = t + 256 * j;
        if (i < NCAPS) { xr[j][0] = x4[2 * i]; xr[j][1] = x4[2 * i + 1]; }
    }
    float blog[5][NCLS];
    #pragma unroll
    for (int j = 0; j < 5; ++j)
        #pragma unroll
        for (int c = 0; c < NCLS; ++c) blog[j][c] = 0.f;
    const float4* W4 = reinterpret_cast<const float4*>(W);
    for (int it = 0; it < 3; ++it) {
        if (it > 0) {
            for (int c = 0; c < NCLS; ++c) {
                float vp[KDO];
                #pragma unroll
                for (int d = 0; d < KDO; ++d) vp[d] = v_prev[c * KDO + d];
                #pragma unroll
                for (int j = 0; j < 5; ++j) {
                    int i = t + 256 * j;
                    if (i < NCAPS) {
                        size_t wbx = (size_t)(c * NCAPS + i) * 32;
                        float a = 0.f;
                        #pragma unroll
                        for (int d = 0; d < KDO; ++d) {
                            float4 w0 = W4[wbx + 2 * d]; float4 w1 = W4[wbx + 2 * d + 1];
                            float u = w0.x*xr[j][0].x + w0.y*xr[j][0].y + w0.z*xr[j][0].z
                                    + w0.w*xr[j][0].w + w1.x*xr[j][1].x + w1.y*xr[j][1].y
                                    + w1.z*xr[j][1].z + w1.w*xr[j][1].w;
                            a += u * vp[d];
                        }
                        blog[j][c] += a;
                    }
                }
            }
        }
        float sm2[5], sid2[5];
        #pragma unroll
        for (int j = 0; j < 5; ++j) {
            int i = t + 256 * j;
            if (i < NCAPS) {
                float m = blog[j][0];
                #pragma unroll
                for (int c = 1; c < NCLS; ++c) m = fmaxf(m, blog[j][c]);
                float den = 0.f;
                #pragma unroll
                for (int c = 0; c < NCLS; ++c) den += __expf(blog[j][c] - m);
                sm2[j] = m; sid2[j] = 1.f / den;
            }
        }
        for (int c = 0; c < NCLS; ++c) {
            float acc[KDO];
            #pragma unroll
            for (int d = 0; d < KDO; ++d) acc[d] = 0.f;
            #pragma unroll
            for (int j = 0; j < 5; ++j) {
                int i = t + 256 * j;
                if (i < NCAPS) {
                    float wq = __expf(blog[j][c] - sm2[j]) * sid2[j];
                    size_t wbx = (size_t)(c * NCAPS + i) * 32;
                    #pragma unroll
                    for (int d = 0; d < KDO; ++d) {
                        float4 w0 = W4[wbx + 2 * d]; float4 w1 = W4[wbx + 2 * d + 1];
                        float u = w0.x*xr[j][0].x + w0.y*xr[j][0].y + w0.z*xr[j][0].z
                                + w0.w*xr[j][0].w + w1.x*xr[j][1].x + w1.y*xr[j][1].y
                                + w1.z*xr[j][1].z + w1.w*xr[j][1].w;
                        acc[d] += wq * u;
                    }
                }
            }
            #pragma unroll
            for (int d = 0; d < KDO; ++d) {
                float v = acc[d];
                v += __shfl_xor(v, 32, 64); v += __shfl_xor(v, 16, 64);
                v += __shfl_xor(v,  8, 64); v += __shfl_xor(v,  4, 64);
                v += __shfl_xor(v,  2, 64); v += __shfl_xor(v,  1, 64);
                if (lane == 0) redf[(c * 4 + wave) * KDO + d] = v;
            }
        }
        __syncthreads();
        if (t < NCLS * KDO) {
            int c = t >> 4, d = t & 15;
            float s = redf[(c*4+0)*KDO+d] + redf[(c*4+1)*KDO+d]
                    + redf[(c*4+2)*KDO+d] + redf[(c*4+3)*KDO+d];
            float nsq = s * s;
            nsq += __shfl_xor(nsq, 8, 16); nsq += __shfl_xor(nsq, 4, 16);
            nsq += __shfl_xor(nsq, 2, 16); nsq += __shfl_xor(nsq, 1, 16);
            float scale = sqrtf(nsq) / (1.f + nsq);
            float vv = s * scale;
            v_prev[t] = vv;
            if (it == 2) out[(size_t)b * NCLS * KDO + t] = vv;
        }
        __syncthreads();
    }
}

extern "C" void kernel_launch(void* const* d_in, const int* in_sizes, int n_in,
                              void* d_out, int out_size, void* d_ws, size_t ws_size,
                              hipStream_t stream) {
    const float* x = (const float*)d_in[0];              // [256, 1152, 8] fp32
    const float4* W4 = (const float4*)d_in[1];           // [10, 1152, 1, 16, 8] fp32
    float* out = (float*)d_out;                          // [256, 10, 1, 16] fp32
    (void)in_sizes; (void)n_in; (void)out_size;

    const size_t WT = (size_t)NCLS * KDO * NCAPS * sizeof(u4);            //  2.95 MB
    const size_t XH = (size_t)NB * NCAPS * sizeof(u4);                    //  4.72 MB
    const size_t UT = (size_t)NB * NCLS * 2 * NCAPS * sizeof(u4);         // 94.37 MB
    const size_t BL = (size_t)NB * NCLS * NCAPS * sizeof(float);          // 11.80 MB
    const size_t WB = (size_t)NB * NCLS * NCAPS * sizeof(unsigned short); //  5.90 MB
    const size_t VP = (size_t)NB * NCLS * 8 * sizeof(unsigned);           //   80 KB
    const size_t need = WT + XH + UT + BL + WB + 2 * VP;                  // ~120 MB

    if (ws_size >= need) {
        char* p = (char*)d_ws;
        u4* Wt             = (u4*)p;             p += WT;
        u4* xp             = (u4*)p;             p += XH;
        u4* ut             = (u4*)p;             p += UT;
        float* blog        = (float*)p;          p += BL;
        unsigned short* wb = (unsigned short*)p; p += WB;
        unsigned* v0       = (unsigned*)p;       p += VP;
        unsigned* v1       = (unsigned*)p;

        int totalW = NCLS * NCAPS * KDO;
        int totalX = NB * NCAPS;
        pack_W_f16<<<dim3((totalW + 255) / 256), dim3(256), 0, stream>>>(W4, Wt);
        pack_x_f16<<<dim3((totalX + 255) / 256), dim3(256), 0, stream>>>(
            (const float4*)x, xp);
        k_uhat<<<dim3(NCH, NB / BBAT, NCLS / 2), dim3(CHUNK), 0, stream>>>(Wt, xp, ut);
        k_sv<<<dim3(NB * NCLS), dim3(256), 0, stream>>>(ut, nullptr, 0.1f, v0, out, 0);
        k_logits<<<dim3(NCH, NB), dim3(CHUNK), 0, stream>>>(ut, v0, blog, wb, 1);
        k_sv<<<dim3(NB * NCLS), dim3(256), 0, stream>>>(ut, wb, 1.f, v1, out, 0);
        k_logits<<<dim3(NCH, NB), dim3(CHUNK), 0, stream>>>(ut, v1, blog, wb, 0);
        k_sv<<<dim3(NB * NCLS), dim3(256), 0, stream>>>(ut, wb, 1.f, v0, out, 1);
    } else {
        caps_routing_fb<<<dim3(NB), dim3(256), 0, stream>>>(x, (const float*)d_in[1], out);
    }
}